// Round 1
// baseline (531.266 us; speedup 1.0000x reference)
//
#include <hip/hip_runtime.h>
#include <math.h>

#define N_ 2048
#define D_ 1024
#define TOPK 10
#define TOPK_HALF 5

// ---------- row-normalize t (and produce sum of squares of t_norm) ----------
__global__ __launch_bounds__(256) void tnorm_kernel(const float* __restrict__ t,
                                                    float* __restrict__ tn,
                                                    float* __restrict__ tt) {
  int row = blockIdx.x;
  const float* rp = t + (size_t)row * D_;
  float* op = tn + (size_t)row * D_;
  __shared__ float red[256];
  int tid = threadIdx.x;
  float s = 0.f;
  for (int k = tid; k < D_; k += 256) { float v = rp[k]; s += v * v; }
  red[tid] = s; __syncthreads();
  for (int st = 128; st > 0; st >>= 1) { if (tid < st) red[tid] += red[tid + st]; __syncthreads(); }
  float denom = fmaxf(sqrtf(red[0]), 1e-12f);
  __syncthreads();
  float s2 = 0.f;
  for (int k = tid; k < D_; k += 256) { float v = rp[k] / denom; op[k] = v; s2 += v * v; }
  red[tid] = s2; __syncthreads();
  for (int st = 128; st > 0; st >>= 1) { if (tid < st) red[tid] += red[tid + st]; __syncthreads(); }
  if (tid == 0) tt[row] = red[0];
}

// ---------- per-row sum of squares (for s_emb) ----------
__global__ __launch_bounds__(256) void sumsq_kernel(const float* __restrict__ a,
                                                    float* __restrict__ out) {
  int row = blockIdx.x;
  const float* rp = a + (size_t)row * D_;
  __shared__ float red[256];
  int tid = threadIdx.x;
  float s = 0.f;
  for (int k = tid; k < D_; k += 256) { float v = rp[k]; s += v * v; }
  red[tid] = s; __syncthreads();
  for (int st = 128; st > 0; st >>= 1) { if (tid < st) red[tid] += red[tid + st]; __syncthreads(); }
  if (tid == 0) out[row] = red[0];
}

// ---------- tiled fp32 Gram: out = f(rn[i] + rn[j] - 2*A[i].A[j]) ----------
// MODE 0: W_P = exp(-max(d2,0)); MODE 1: S = sqrt(max(d2,0))
template <int MODE>
__global__ void __launch_bounds__(256) gram_kernel(const float* __restrict__ A,
                                                   const float* __restrict__ rn,
                                                   float* __restrict__ out) {
  __shared__ float As[16][68];  // +4 pad: keeps 16B alignment, breaks 4-way write conflict
  __shared__ float Bs[16][68];
  int tid = threadIdx.x;
  int tx = tid & 15, ty = tid >> 4;
  int i0 = blockIdx.y * 64, j0 = blockIdx.x * 64;
  int lrow = tid >> 2;          // 0..63
  int lk = (tid & 3) << 2;      // 0,4,8,12
  const float* Ap = A + (size_t)(i0 + lrow) * D_ + lk;
  const float* Bp = A + (size_t)(j0 + lrow) * D_ + lk;
  float acc[4][4] = {};
  for (int k0 = 0; k0 < D_; k0 += 16) {
    float4 av = *(const float4*)(Ap + k0);
    float4 bv = *(const float4*)(Bp + k0);
    __syncthreads();
    As[lk + 0][lrow] = av.x; As[lk + 1][lrow] = av.y; As[lk + 2][lrow] = av.z; As[lk + 3][lrow] = av.w;
    Bs[lk + 0][lrow] = bv.x; Bs[lk + 1][lrow] = bv.y; Bs[lk + 2][lrow] = bv.z; Bs[lk + 3][lrow] = bv.w;
    __syncthreads();
#pragma unroll
    for (int kk = 0; kk < 16; kk++) {
      float4 a = *(const float4*)&As[kk][ty << 2];
      float4 b = *(const float4*)&Bs[kk][tx << 2];
      acc[0][0] += a.x * b.x; acc[0][1] += a.x * b.y; acc[0][2] += a.x * b.z; acc[0][3] += a.x * b.w;
      acc[1][0] += a.y * b.x; acc[1][1] += a.y * b.y; acc[1][2] += a.y * b.z; acc[1][3] += a.y * b.w;
      acc[2][0] += a.z * b.x; acc[2][1] += a.z * b.y; acc[2][2] += a.z * b.z; acc[2][3] += a.z * b.w;
      acc[3][0] += a.w * b.x; acc[3][1] += a.w * b.y; acc[3][2] += a.w * b.z; acc[3][3] += a.w * b.w;
    }
  }
#pragma unroll
  for (int r = 0; r < 4; r++) {
    int i = i0 + (ty << 2) + r;
    float ri = rn[i];
#pragma unroll
    for (int c = 0; c < 4; c++) {
      int j = j0 + (tx << 2) + c;
      float d2 = fmaxf(ri + rn[j] - 2.f * acc[r][c], 0.f);
      float o = (MODE == 0) ? expf(-d2) : sqrtf(d2);
      out[(size_t)i * N_ + j] = o;
    }
  }
}

// ---------- top-10 per row (10 argmax passes, lowest-index tiebreak) ----------
__global__ __launch_bounds__(256) void topk_kernel(const float* __restrict__ W_P,
                                                   int* __restrict__ idx) {
  int row = blockIdx.x;
  __shared__ float vals[N_];
  __shared__ float rv[256];
  __shared__ int ri[256];
  int tid = threadIdx.x;
  const float* rp = W_P + (size_t)row * N_;
  for (int j = tid; j < N_; j += 256) vals[j] = rp[j];
  __syncthreads();
  for (int t = 0; t < TOPK; t++) {
    float bv = -2.f; int bi = 0;
    for (int j = tid; j < N_; j += 256) {
      float v = vals[j];
      if (v > bv) { bv = v; bi = j; }   // ascending j => lowest index kept on tie
    }
    rv[tid] = bv; ri[tid] = bi;
    __syncthreads();
    for (int st = 128; st > 0; st >>= 1) {
      if (tid < st) {
        float v2 = rv[tid + st]; int i2 = ri[tid + st];
        if (v2 > rv[tid] || (v2 == rv[tid] && i2 < ri[tid])) { rv[tid] = v2; ri[tid] = i2; }
      }
      __syncthreads();
    }
    if (tid == 0) { idx[row * TOPK + t] = ri[0]; vals[ri[0]] = -1.f; }
    __syncthreads();
  }
}

// ---------- mutual kNN adjacency (V), as per-row neighbor lists ----------
__global__ void mutual_kernel(const int* __restrict__ idx, int* __restrict__ nbr,
                              int* __restrict__ deg) {
  int i = blockIdx.x * blockDim.x + threadIdx.x;
  if (i >= N_) return;
  int cnt = 0;
  for (int k = 0; k < TOPK; k++) {
    int j = idx[i * TOPK + k];
    bool mut = false;
    for (int l = 0; l < TOPK; l++)
      if (idx[j * TOPK + l] == i) mut = true;
    if (mut) nbr[i * TOPK + cnt++] = j;
  }
  deg[i] = cnt;
}

// ---------- overlap[i][k] = |nbr(i) ∩ nbr(j_k)| for k-th neighbor ----------
__global__ void overlap_kernel(const int* __restrict__ nbr, const int* __restrict__ deg,
                               float* __restrict__ ovl) {
  int i = blockIdx.x * blockDim.x + threadIdx.x;
  if (i >= N_) return;
  int di = deg[i];
  for (int k = 0; k < di; k++) {
    int j = nbr[i * TOPK + k];
    int dj = deg[j];
    int c = 0;
    for (int a = 0; a < di; a++) {
      int na = nbr[i * TOPK + a];
      for (int b = 0; b < dj; b++)
        if (nbr[j * TOPK + b] == na) c++;
    }
    ovl[i * TOPK + k] = (float)c;
  }
}

__global__ void zero_kernel(float* __restrict__ p, size_t n) {
  size_t i = (size_t)blockIdx.x * blockDim.x + threadIdx.x;
  size_t stride = (size_t)gridDim.x * blockDim.x;
  for (; i < n; i += stride) p[i] = 0.f;
}

// ---------- dense symmetric W_C = 0.5*(W_C_hat + W_C_hat^T) via scatter ----------
// W_C_hat[i][col] = (1/5) * sum_{m in idx[i][:5]} overlap[m][col]/deg[m]  (at V positions)
__global__ void scatter_kernel(const int* __restrict__ idx, const int* __restrict__ nbr,
                               const int* __restrict__ deg, const float* __restrict__ ovl,
                               float* __restrict__ W_C) {
  int i = blockIdx.x * blockDim.x + threadIdx.x;
  if (i >= N_) return;
  for (int mi = 0; mi < TOPK_HALF; mi++) {
    int m = idx[i * TOPK + mi];
    int dm = deg[m];
    float invd = 1.0f / (float)dm;
    for (int k = 0; k < dm; k++) {
      int col = nbr[m * TOPK + k];
      float v = ovl[m * TOPK + k] * invd * 0.1f;  // *(1/5 mean) * (1/2 symmetrize)
      atomicAdd(&W_C[(size_t)i * N_ + col], v);
      atomicAdd(&W_C[(size_t)col * N_ + i], v);
    }
  }
}

// ---------- per-row mean of raw S distances ----------
__global__ __launch_bounds__(256) void rowmean_kernel(const float* __restrict__ S,
                                                      float* __restrict__ rowmean) {
  int row = blockIdx.x;
  const float* rp = S + (size_t)row * N_;
  __shared__ float red[256];
  int tid = threadIdx.x;
  float s = 0.f;
  for (int j = tid; j < N_; j += 256) s += rp[j];
  red[tid] = s; __syncthreads();
  for (int st = 128; st > 0; st >>= 1) { if (tid < st) red[tid] += red[tid + st]; __syncthreads(); }
  if (tid == 0) rowmean[row] = red[0] / (float)N_;
}

// ---------- fused loss: per-row partial sums ----------
__global__ __launch_bounds__(256) void loss_kernel(const float* __restrict__ W_P,
                                                   const float* __restrict__ W_C,
                                                   const float* __restrict__ S,
                                                   const float* __restrict__ rowmean,
                                                   float* __restrict__ partials) {
  int i = blockIdx.x;
  int tid = threadIdx.x;
  float rm = rowmean[i];
  const float* wpr = W_P + (size_t)i * N_;
  const float* wcr = W_C + (size_t)i * N_;
  const float* sr = S + (size_t)i * N_;
  float local = 0.f;
  for (int j = tid; j < N_; j += 256) {
    if (j == i) continue;
    float W = 0.5f * (wpr[j] + wcr[j]);
    float s = sr[j] / rm;
    float d = fmaxf(1.0f - s, 0.f);
    local += s * s * W + d * d * (1.0f - W);
  }
  __shared__ float red[256];
  red[tid] = local; __syncthreads();
  for (int st = 128; st > 0; st >>= 1) { if (tid < st) red[tid] += red[tid + st]; __syncthreads(); }
  if (tid == 0) partials[i] = red[0];
}

__global__ __launch_bounds__(256) void finalize_kernel(const float* __restrict__ partials,
                                                       float* __restrict__ out) {
  __shared__ float red[256];
  int tid = threadIdx.x;
  float s = 0.f;
  for (int i = tid; i < N_; i += 256) s += partials[i];
  red[tid] = s; __syncthreads();
  for (int st = 128; st > 0; st >>= 1) { if (tid < st) red[tid] += red[tid + st]; __syncthreads(); }
  if (tid == 0) out[0] = red[0] / ((float)N_ * (float)(N_ - 1));
}

extern "C" void kernel_launch(void* const* d_in, const int* in_sizes, int n_in,
                              void* d_out, int out_size, void* d_ws, size_t ws_size,
                              hipStream_t stream) {
  const float* s_emb = (const float*)d_in[0];
  const float* t_emb = (const float*)d_in[1];
  float* out = (float*)d_out;
  float* ws = (float*)d_ws;

  const size_t NN = (size_t)N_ * N_;
  float* t_norm = ws;                                // N*D
  float* W_P = t_norm + (size_t)N_ * D_;             // N*N
  float* S_raw = W_P + NN;                           // N*N
  float* W_C = S_raw + NN;                           // N*N
  float* tt = W_C + NN;                              // N
  float* ss = tt + N_;                               // N
  float* rowmean = ss + N_;                          // N
  float* partials = rowmean + N_;                    // N
  float* ovl = partials + N_;                        // N*TOPK
  int* idx = (int*)(ovl + (size_t)N_ * TOPK);        // N*TOPK
  int* nbr = idx + (size_t)N_ * TOPK;                // N*TOPK
  int* deg = nbr + (size_t)N_ * TOPK;                // N

  tnorm_kernel<<<N_, 256, 0, stream>>>(t_emb, t_norm, tt);
  sumsq_kernel<<<N_, 256, 0, stream>>>(s_emb, ss);

  dim3 g(N_ / 64, N_ / 64);
  gram_kernel<0><<<g, 256, 0, stream>>>(t_norm, tt, W_P);
  gram_kernel<1><<<g, 256, 0, stream>>>(s_emb, ss, S_raw);

  topk_kernel<<<N_, 256, 0, stream>>>(W_P, idx);
  mutual_kernel<<<N_ / 256, 256, 0, stream>>>(idx, nbr, deg);
  overlap_kernel<<<N_ / 256, 256, 0, stream>>>(nbr, deg, ovl);

  zero_kernel<<<1024, 256, 0, stream>>>(W_C, NN);
  scatter_kernel<<<N_ / 256, 256, 0, stream>>>(idx, nbr, deg, ovl, W_C);

  rowmean_kernel<<<N_, 256, 0, stream>>>(S_raw, rowmean);
  loss_kernel<<<N_, 256, 0, stream>>>(W_P, W_C, S_raw, rowmean, partials);
  finalize_kernel<<<1, 256, 0, stream>>>(partials, out);
}

// Round 2
// 230.141 us; speedup vs baseline: 2.3084x; 2.3084x over previous
//
#include <hip/hip_runtime.h>
#include <math.h>

#define N_ 2048
#define D_ 1024
#define TOPK 10
#define TOPK_HALF 5

typedef __attribute__((ext_vector_type(8))) short short8;
typedef __attribute__((ext_vector_type(4))) float floatx4;

__device__ __forceinline__ short f2bf(float f) {
  unsigned u = __float_as_uint(f);
  unsigned r = (u + 0x7fffu + ((u >> 16) & 1u)) >> 16;
  return (short)r;
}

__device__ __forceinline__ void gld_lds16(const short* g, short* l) {
  __builtin_amdgcn_global_load_lds(
      (const __attribute__((address_space(1))) unsigned int*)(g),
      (__attribute__((address_space(3))) unsigned int*)(l), 16, 0, 0);
}

// ---------- row-normalize t -> bf16, tt = fp32 sum of normalized squares ----------
__global__ __launch_bounds__(256) void tnorm_kernel(const float* __restrict__ t,
                                                    short* __restrict__ tb,
                                                    float* __restrict__ tt) {
  int row = blockIdx.x;
  const float* rp = t + (size_t)row * D_;
  short* op = tb + (size_t)row * D_;
  __shared__ float red[256];
  int tid = threadIdx.x;
  float s = 0.f;
  for (int k = tid; k < D_; k += 256) { float v = rp[k]; s += v * v; }
  red[tid] = s; __syncthreads();
  for (int st = 128; st > 0; st >>= 1) { if (tid < st) red[tid] += red[tid + st]; __syncthreads(); }
  float denom = fmaxf(sqrtf(red[0]), 1e-12f);
  __syncthreads();
  float s2 = 0.f;
  for (int k = tid; k < D_; k += 256) { float v = rp[k] / denom; op[k] = f2bf(v); s2 += v * v; }
  red[tid] = s2; __syncthreads();
  for (int st = 128; st > 0; st >>= 1) { if (tid < st) red[tid] += red[tid + st]; __syncthreads(); }
  if (tid == 0) tt[row] = red[0];
}

// ---------- convert s to bf16, ss = fp32 row sum of squares of original ----------
__global__ __launch_bounds__(256) void sconv_kernel(const float* __restrict__ a,
                                                    short* __restrict__ ab,
                                                    float* __restrict__ out) {
  int row = blockIdx.x;
  const float* rp = a + (size_t)row * D_;
  short* op = ab + (size_t)row * D_;
  __shared__ float red[256];
  int tid = threadIdx.x;
  float s = 0.f;
  for (int k = tid; k < D_; k += 256) { float v = rp[k]; op[k] = f2bf(v); s += v * v; }
  red[tid] = s; __syncthreads();
  for (int st = 128; st > 0; st >>= 1) { if (tid < st) red[tid] += red[tid + st]; __syncthreads(); }
  if (tid == 0) out[row] = red[0];
}

// ---------- fused bf16-MFMA Gram for both matrices (blockIdx.z selects) ----------
// z==0: W_P = exp(-max(d2,0)) from t_bf/tt ; z==1: S = sqrt(max(d2,0)) from s_bf/ss
__global__ __launch_bounds__(256) void gram_mfma_kernel(
    const short* __restrict__ Tb, const short* __restrict__ Sb,
    const float* __restrict__ tt, const float* __restrict__ ss,
    float* __restrict__ WP, float* __restrict__ Sout) {
  const int mode = blockIdx.z;
  const short* A = mode ? Sb : Tb;
  const float* rn = mode ? ss : tt;
  float* out = mode ? Sout : WP;

  __shared__ __align__(16) short As[128 * 64];
  __shared__ __align__(16) short Bs[128 * 64];

  int tid = threadIdx.x;
  int w = tid >> 6, lane = tid & 63;
  int i0 = blockIdx.y * 128, j0 = blockIdx.x * 128;
  int wr = w >> 1, wc = w & 1;
  int quad = lane >> 4, l16 = lane & 15;

  floatx4 acc[4][4] = {};

  int srow = w * 32 + (lane >> 3);   // row staged at q=0; +8 per q
  int scol = (lane & 7) * 8;         // bf16 element offset within 64-wide K slab
  const short* Ag = A + (size_t)(i0 + srow) * D_ + scol;
  const short* Bg = A + (size_t)(j0 + srow) * D_ + scol;
  short* Al = As + srow * 64 + scol;
  short* Bl = Bs + srow * 64 + scol;

  for (int k0 = 0; k0 < D_; k0 += 64) {
    __syncthreads();
#pragma unroll
    for (int q = 0; q < 4; q++) {
      gld_lds16(Ag + k0 + (size_t)q * 8 * D_, Al + q * 8 * 64);
      gld_lds16(Bg + k0 + (size_t)q * 8 * D_, Bl + q * 8 * 64);
    }
    __syncthreads();
#pragma unroll
    for (int ks = 0; ks < 64; ks += 32) {
      short8 af[4], bfr[4];
#pragma unroll
      for (int mt = 0; mt < 4; mt++)
        af[mt] = *(const short8*)&As[(wr * 64 + mt * 16 + l16) * 64 + ks + quad * 8];
#pragma unroll
      for (int nt = 0; nt < 4; nt++)
        bfr[nt] = *(const short8*)&Bs[(wc * 64 + nt * 16 + l16) * 64 + ks + quad * 8];
#pragma unroll
      for (int mt = 0; mt < 4; mt++)
#pragma unroll
        for (int nt = 0; nt < 4; nt++)
          acc[mt][nt] = __builtin_amdgcn_mfma_f32_16x16x32_bf16(af[mt], bfr[nt], acc[mt][nt], 0, 0, 0);
    }
  }

#pragma unroll
  for (int mt = 0; mt < 4; mt++) {
    int ib = i0 + wr * 64 + mt * 16 + quad * 4;
#pragma unroll
    for (int r = 0; r < 4; r++) {
      int i = ib + r;
      float ri = rn[i];
#pragma unroll
      for (int nt = 0; nt < 4; nt++) {
        int j = j0 + wc * 64 + nt * 16 + l16;
        float d2 = fmaxf(ri + rn[j] - 2.f * acc[mt][nt][r], 0.f);
        float o = (mode == 0) ? expf(-d2) : sqrtf(d2);
        if (i == j) o = (mode == 0) ? 1.f : 0.f;
        out[(size_t)i * N_ + j] = o;
      }
    }
  }
}

// ---------- top-10 per row (10 argmax passes, lowest-index tiebreak) ----------
__global__ __launch_bounds__(256) void topk_kernel(const float* __restrict__ W_P,
                                                   int* __restrict__ idx) {
  int row = blockIdx.x;
  __shared__ float vals[N_];
  __shared__ float wv[4];
  __shared__ int wi[4];
  int tid = threadIdx.x;
  const float* rp = W_P + (size_t)row * N_;
  for (int j = tid; j < N_; j += 256) vals[j] = rp[j];
  __syncthreads();
  for (int t = 0; t < TOPK; t++) {
    float bv = -2.f; int bi = N_;
    for (int j = tid; j < N_; j += 256) {
      float v = vals[j];
      if (v > bv) { bv = v; bi = j; }   // ascending j => lowest index on tie
    }
#pragma unroll
    for (int off = 32; off > 0; off >>= 1) {
      float ov = __shfl_down(bv, off);
      int oi = __shfl_down(bi, off);
      if (ov > bv || (ov == bv && oi < bi)) { bv = ov; bi = oi; }
    }
    int w = tid >> 6;
    if ((tid & 63) == 0) { wv[w] = bv; wi[w] = bi; }
    __syncthreads();
    if (tid == 0) {
      float b0 = wv[0]; int i0 = wi[0];
#pragma unroll
      for (int u = 1; u < 4; u++)
        if (wv[u] > b0 || (wv[u] == b0 && wi[u] < i0)) { b0 = wv[u]; i0 = wi[u]; }
      idx[row * TOPK + t] = i0;
      vals[i0] = -1.f;
    }
    __syncthreads();
  }
}

// ---------- mutual kNN adjacency (V), per-row neighbor lists ----------
__global__ void mutual_kernel(const int* __restrict__ idx, int* __restrict__ nbr,
                              int* __restrict__ deg) {
  int i = blockIdx.x * blockDim.x + threadIdx.x;
  if (i >= N_) return;
  int cnt = 0;
  for (int k = 0; k < TOPK; k++) {
    int j = idx[i * TOPK + k];
    bool mut = false;
    for (int l = 0; l < TOPK; l++)
      if (idx[j * TOPK + l] == i) mut = true;
    if (mut) nbr[i * TOPK + cnt++] = j;
  }
  deg[i] = cnt;
}

// ---------- overlap[i][k] = |nbr(i) ∩ nbr(j_k)|, one thread per (i,k) ----------
__global__ void overlap_kernel(const int* __restrict__ nbr, const int* __restrict__ deg,
                               float* __restrict__ ovl) {
  int t = blockIdx.x * blockDim.x + threadIdx.x;
  int i = t / TOPK, k = t % TOPK;
  if (i >= N_) return;
  int di = deg[i];
  if (k >= di) return;
  int j = nbr[i * TOPK + k];
  int dj = deg[j];
  int c = 0;
  for (int a = 0; a < di; a++) {
    int na = nbr[i * TOPK + a];
    for (int b = 0; b < dj; b++) c += (nbr[j * TOPK + b] == na);
  }
  ovl[i * TOPK + k] = (float)c;
}

__global__ void zero_kernel(float4* __restrict__ p, size_t n4) {
  size_t i = (size_t)blockIdx.x * blockDim.x + threadIdx.x;
  size_t stride = (size_t)gridDim.x * blockDim.x;
  float4 z = {0.f, 0.f, 0.f, 0.f};
  for (; i < n4; i += stride) p[i] = z;
}

// ---------- dense symmetric W_C via atomic scatter ----------
__global__ void scatter_kernel(const int* __restrict__ idx, const int* __restrict__ nbr,
                               const int* __restrict__ deg, const float* __restrict__ ovl,
                               float* __restrict__ W_C) {
  int i = blockIdx.x * blockDim.x + threadIdx.x;
  if (i >= N_) return;
  for (int mi = 0; mi < TOPK_HALF; mi++) {
    int m = idx[i * TOPK + mi];
    int dm = deg[m];
    float invd = 1.0f / (float)dm;
    for (int k = 0; k < dm; k++) {
      int col = nbr[m * TOPK + k];
      float v = ovl[m * TOPK + k] * invd * 0.1f;  // (1/5 mean) * (1/2 symmetrize)
      atomicAdd(&W_C[(size_t)i * N_ + col], v);
      atomicAdd(&W_C[(size_t)col * N_ + i], v);
    }
  }
}

// ---------- per-row mean of raw S distances ----------
__global__ __launch_bounds__(256) void rowmean_kernel(const float* __restrict__ S,
                                                      float* __restrict__ rowmean) {
  int row = blockIdx.x;
  const float4* rp = (const float4*)(S + (size_t)row * N_);
  __shared__ float red[256];
  int tid = threadIdx.x;
  float s = 0.f;
  for (int j = tid; j < N_ / 4; j += 256) { float4 v = rp[j]; s += v.x + v.y + v.z + v.w; }
  red[tid] = s; __syncthreads();
  for (int st = 128; st > 0; st >>= 1) { if (tid < st) red[tid] += red[tid + st]; __syncthreads(); }
  if (tid == 0) rowmean[row] = red[0] / (float)N_;
}

// ---------- fused loss: per-row partial sums (full row, then subtract diag) ----------
__global__ __launch_bounds__(256) void loss_kernel(const float* __restrict__ W_P,
                                                   const float* __restrict__ W_C,
                                                   const float* __restrict__ S,
                                                   const float* __restrict__ rowmean,
                                                   float* __restrict__ partials) {
  int i = blockIdx.x;
  int tid = threadIdx.x;
  float rminv = 1.f / rowmean[i];
  const float4* wpr = (const float4*)(W_P + (size_t)i * N_);
  const float4* wcr = (const float4*)(W_C + (size_t)i * N_);
  const float4* sr = (const float4*)(S + (size_t)i * N_);
  float local = 0.f;
  for (int j4 = tid; j4 < N_ / 4; j4 += 256) {
    float4 wp = wpr[j4], wc = wcr[j4], sv = sr[j4];
#pragma unroll
    for (int c = 0; c < 4; c++) {
      float W = 0.5f * (((const float*)&wp)[c] + ((const float*)&wc)[c]);
      float s = ((const float*)&sv)[c] * rminv;
      float d = fmaxf(1.0f - s, 0.f);
      local += s * s * W + d * d * (1.0f - W);
    }
  }
  __shared__ float red[256];
  red[tid] = local; __syncthreads();
  for (int st = 128; st > 0; st >>= 1) { if (tid < st) red[tid] += red[tid + st]; __syncthreads(); }
  if (tid == 0) {
    // diag term: s_ii=0 -> pull=0, push=(1-W_ii); subtract it
    float Wii = 0.5f * (W_P[(size_t)i * N_ + i] + W_C[(size_t)i * N_ + i]);
    partials[i] = red[0] - (1.0f - Wii);
  }
}

__global__ __launch_bounds__(256) void finalize_kernel(const float* __restrict__ partials,
                                                       float* __restrict__ out) {
  __shared__ float red[256];
  int tid = threadIdx.x;
  float s = 0.f;
  for (int i = tid; i < N_; i += 256) s += partials[i];
  red[tid] = s; __syncthreads();
  for (int st = 128; st > 0; st >>= 1) { if (tid < st) red[tid] += red[tid + st]; __syncthreads(); }
  if (tid == 0) out[0] = red[0] / ((float)N_ * (float)(N_ - 1));
}

extern "C" void kernel_launch(void* const* d_in, const int* in_sizes, int n_in,
                              void* d_out, int out_size, void* d_ws, size_t ws_size,
                              hipStream_t stream) {
  const float* s_emb = (const float*)d_in[0];
  const float* t_emb = (const float*)d_in[1];
  float* out = (float*)d_out;

  const size_t NN = (size_t)N_ * N_;
  const size_t ND = (size_t)N_ * D_;
  short* t_bf = (short*)d_ws;                        // N*D bf16
  short* s_bf = t_bf + ND;                           // N*D bf16
  float* W_P = (float*)(s_bf + ND);                  // N*N
  float* S_raw = W_P + NN;                           // N*N
  float* W_C = S_raw + NN;                           // N*N
  float* tt = W_C + NN;                              // N
  float* ss = tt + N_;                               // N
  float* rowmean = ss + N_;                          // N
  float* partials = rowmean + N_;                    // N
  float* ovl = partials + N_;                        // N*TOPK
  int* idx = (int*)(ovl + (size_t)N_ * TOPK);        // N*TOPK
  int* nbr = idx + (size_t)N_ * TOPK;                // N*TOPK
  int* deg = nbr + (size_t)N_ * TOPK;                // N

  tnorm_kernel<<<N_, 256, 0, stream>>>(t_emb, t_bf, tt);
  sconv_kernel<<<N_, 256, 0, stream>>>(s_emb, s_bf, ss);

  dim3 g(N_ / 128, N_ / 128, 2);
  gram_mfma_kernel<<<g, 256, 0, stream>>>(t_bf, s_bf, tt, ss, W_P, S_raw);

  topk_kernel<<<N_, 256, 0, stream>>>(W_P, idx);
  mutual_kernel<<<N_ / 256, 256, 0, stream>>>(idx, nbr, deg);
  overlap_kernel<<<(N_ * TOPK + 255) / 256, 256, 0, stream>>>(nbr, deg, ovl);

  zero_kernel<<<1024, 256, 0, stream>>>((float4*)W_C, NN / 4);
  scatter_kernel<<<N_ / 256, 256, 0, stream>>>(idx, nbr, deg, ovl, W_C);

  rowmean_kernel<<<N_, 256, 0, stream>>>(S_raw, rowmean);
  loss_kernel<<<N_, 256, 0, stream>>>(W_P, W_C, S_raw, rowmean, partials);
  finalize_kernel<<<1, 256, 0, stream>>>(partials, out);
}

// Round 3
// 162.487 us; speedup vs baseline: 3.2696x; 1.4164x over previous
//
#include <hip/hip_runtime.h>
#include <math.h>

#define N_ 2048
#define D_ 1024
#define TOPK 10
#define TOPK_HALF 5

typedef __attribute__((ext_vector_type(8))) short short8;
typedef __attribute__((ext_vector_type(4))) float floatx4;

__device__ __forceinline__ short f2bf(float f) {
  unsigned u = __float_as_uint(f);
  unsigned r = (u + 0x7fffu + ((u >> 16) & 1u)) >> 16;
  return (short)r;
}

__device__ __forceinline__ void gld_lds16(const short* g, short* l) {
  __builtin_amdgcn_global_load_lds(
      (const __attribute__((address_space(1))) unsigned int*)(g),
      (__attribute__((address_space(3))) unsigned int*)(l), 16, 0, 0);
}

// ---------- row-normalize t -> bf16, tt = fp32 sum of normalized squares ----------
__global__ __launch_bounds__(256) void tnorm_kernel(const float* __restrict__ t,
                                                    short* __restrict__ tb,
                                                    float* __restrict__ tt) {
  int row = blockIdx.x;
  const float* rp = t + (size_t)row * D_;
  short* op = tb + (size_t)row * D_;
  __shared__ float red[256];
  int tid = threadIdx.x;
  float s = 0.f;
  for (int k = tid; k < D_; k += 256) { float v = rp[k]; s += v * v; }
  red[tid] = s; __syncthreads();
  for (int st = 128; st > 0; st >>= 1) { if (tid < st) red[tid] += red[tid + st]; __syncthreads(); }
  float denom = fmaxf(sqrtf(red[0]), 1e-12f);
  __syncthreads();
  float s2 = 0.f;
  for (int k = tid; k < D_; k += 256) { float v = rp[k] / denom; op[k] = f2bf(v); s2 += v * v; }
  red[tid] = s2; __syncthreads();
  for (int st = 128; st > 0; st >>= 1) { if (tid < st) red[tid] += red[tid + st]; __syncthreads(); }
  if (tid == 0) tt[row] = red[0];
}

// ---------- convert s to bf16, ss = fp32 row sum of squares of original ----------
__global__ __launch_bounds__(256) void sconv_kernel(const float* __restrict__ a,
                                                    short* __restrict__ ab,
                                                    float* __restrict__ out) {
  int row = blockIdx.x;
  const float* rp = a + (size_t)row * D_;
  short* op = ab + (size_t)row * D_;
  __shared__ float red[256];
  int tid = threadIdx.x;
  float s = 0.f;
  for (int k = tid; k < D_; k += 256) { float v = rp[k]; op[k] = f2bf(v); s += v * v; }
  red[tid] = s; __syncthreads();
  for (int st = 128; st > 0; st >>= 1) { if (tid < st) red[tid] += red[tid + st]; __syncthreads(); }
  if (tid == 0) out[row] = red[0];
}

// ---------- fused bf16-MFMA Gram for both matrices (blockIdx.z selects) ----------
// z==0: W_P = exp(-max(d2,0)) from t_bf/tt ; z==1: S = sqrt(max(d2,0)) from s_bf/ss
__global__ __launch_bounds__(256) void gram_mfma_kernel(
    const short* __restrict__ Tb, const short* __restrict__ Sb,
    const float* __restrict__ tt, const float* __restrict__ ss,
    float* __restrict__ WP, float* __restrict__ Sout) {
  const int mode = blockIdx.z;
  const short* A = mode ? Sb : Tb;
  const float* rn = mode ? ss : tt;
  float* out = mode ? Sout : WP;

  __shared__ __align__(16) short As[128 * 64];
  __shared__ __align__(16) short Bs[128 * 64];

  int tid = threadIdx.x;
  int w = tid >> 6, lane = tid & 63;
  int i0 = blockIdx.y * 128, j0 = blockIdx.x * 128;
  int wr = w >> 1, wc = w & 1;
  int quad = lane >> 4, l16 = lane & 15;

  floatx4 acc[4][4] = {};

  int srow = w * 32 + (lane >> 3);   // row staged at q=0; +8 per q
  int scol = (lane & 7) * 8;         // bf16 element offset within 64-wide K slab
  const short* Ag = A + (size_t)(i0 + srow) * D_ + scol;
  const short* Bg = A + (size_t)(j0 + srow) * D_ + scol;
  short* Al = As + srow * 64 + scol;
  short* Bl = Bs + srow * 64 + scol;

  for (int k0 = 0; k0 < D_; k0 += 64) {
    __syncthreads();
#pragma unroll
    for (int q = 0; q < 4; q++) {
      gld_lds16(Ag + k0 + (size_t)q * 8 * D_, Al + q * 8 * 64);
      gld_lds16(Bg + k0 + (size_t)q * 8 * D_, Bl + q * 8 * 64);
    }
    __syncthreads();
#pragma unroll
    for (int ks = 0; ks < 64; ks += 32) {
      short8 af[4], bfr[4];
#pragma unroll
      for (int mt = 0; mt < 4; mt++)
        af[mt] = *(const short8*)&As[(wr * 64 + mt * 16 + l16) * 64 + ks + quad * 8];
#pragma unroll
      for (int nt = 0; nt < 4; nt++)
        bfr[nt] = *(const short8*)&Bs[(wc * 64 + nt * 16 + l16) * 64 + ks + quad * 8];
#pragma unroll
      for (int mt = 0; mt < 4; mt++)
#pragma unroll
        for (int nt = 0; nt < 4; nt++)
          acc[mt][nt] = __builtin_amdgcn_mfma_f32_16x16x32_bf16(af[mt], bfr[nt], acc[mt][nt], 0, 0, 0);
    }
  }

#pragma unroll
  for (int mt = 0; mt < 4; mt++) {
    int ib = i0 + wr * 64 + mt * 16 + quad * 4;
#pragma unroll
    for (int r = 0; r < 4; r++) {
      int i = ib + r;
      float ri = rn[i];
#pragma unroll
      for (int nt = 0; nt < 4; nt++) {
        int j = j0 + wc * 64 + nt * 16 + l16;
        float d2 = fmaxf(ri + rn[j] - 2.f * acc[mt][nt][r], 0.f);
        float o = (mode == 0) ? expf(-d2) : sqrtf(d2);
        if (i == j) o = (mode == 0) ? 1.f : 0.f;
        out[(size_t)i * N_ + j] = o;
      }
    }
  }
}

// ---------- top-10 per row (10 argmax passes, lowest-index tiebreak) ----------
__global__ __launch_bounds__(256) void topk_kernel(const float* __restrict__ W_P,
                                                   int* __restrict__ idx) {
  int row = blockIdx.x;
  __shared__ float vals[N_];
  __shared__ float wv[4];
  __shared__ int wi[4];
  int tid = threadIdx.x;
  const float* rp = W_P + (size_t)row * N_;
  for (int j = tid; j < N_; j += 256) vals[j] = rp[j];
  __syncthreads();
  for (int t = 0; t < TOPK; t++) {
    float bv = -2.f; int bi = N_;
    for (int j = tid; j < N_; j += 256) {
      float v = vals[j];
      if (v > bv) { bv = v; bi = j; }   // ascending j => lowest index on tie
    }
#pragma unroll
    for (int off = 32; off > 0; off >>= 1) {
      float ov = __shfl_down(bv, off);
      int oi = __shfl_down(bi, off);
      if (ov > bv || (ov == bv && oi < bi)) { bv = ov; bi = oi; }
    }
    int w = tid >> 6;
    if ((tid & 63) == 0) { wv[w] = bv; wi[w] = bi; }
    __syncthreads();
    if (tid == 0) {
      float b0 = wv[0]; int i0 = wi[0];
#pragma unroll
      for (int u = 1; u < 4; u++)
        if (wv[u] > b0 || (wv[u] == b0 && wi[u] < i0)) { b0 = wv[u]; i0 = wi[u]; }
      idx[row * TOPK + t] = i0;
      vals[i0] = -1.f;
    }
    __syncthreads();
  }
}

// ---------- mutual kNN adjacency (V), per-row neighbor lists ----------
__global__ void mutual_kernel(const int* __restrict__ idx, int* __restrict__ nbr,
                              int* __restrict__ deg) {
  int i = blockIdx.x * blockDim.x + threadIdx.x;
  if (i >= N_) return;
  int cnt = 0;
  for (int k = 0; k < TOPK; k++) {
    int j = idx[i * TOPK + k];
    bool mut = false;
    for (int l = 0; l < TOPK; l++)
      if (idx[j * TOPK + l] == i) mut = true;
    if (mut) nbr[i * TOPK + cnt++] = j;
  }
  deg[i] = cnt;
}

// ---------- overlap[i][k] = |nbr(i) ∩ nbr(j_k)|, one thread per (i,k) ----------
__global__ void overlap_kernel(const int* __restrict__ nbr, const int* __restrict__ deg,
                               float* __restrict__ ovl) {
  int t = blockIdx.x * blockDim.x + threadIdx.x;
  int i = t / TOPK, k = t % TOPK;
  if (i >= N_) return;
  int di = deg[i];
  if (k >= di) return;
  int j = nbr[i * TOPK + k];
  int dj = deg[j];
  int c = 0;
  for (int a = 0; a < di; a++) {
    int na = nbr[i * TOPK + a];
    for (int b = 0; b < dj; b++) c += (nbr[j * TOPK + b] == na);
  }
  ovl[i * TOPK + k] = (float)c;
}

// ---------- per-row mean of raw S distances ----------
__global__ __launch_bounds__(256) void rowmean_kernel(const float* __restrict__ S,
                                                      float* __restrict__ rowmean) {
  int row = blockIdx.x;
  const float4* rp = (const float4*)(S + (size_t)row * N_);
  __shared__ float red[256];
  int tid = threadIdx.x;
  float s = 0.f;
  for (int j = tid; j < N_ / 4; j += 256) { float4 v = rp[j]; s += v.x + v.y + v.z + v.w; }
  red[tid] = s; __syncthreads();
  for (int st = 128; st > 0; st >>= 1) { if (tid < st) red[tid] += red[tid + st]; __syncthreads(); }
  if (tid == 0) rowmean[row] = red[0] / (float)N_;
}

// ---------- dense loss part: sum_j [d^2 + 0.5*W_P*(s^2-d^2)] per row ----------
// diagonal contributes exactly 0.5 (W_P_ii=1, s_ii=0) -> subtracted
__global__ __launch_bounds__(256) void loss_kernel(const float* __restrict__ W_P,
                                                   const float* __restrict__ S,
                                                   const float* __restrict__ rowmean,
                                                   float* __restrict__ partials) {
  int i = blockIdx.x;
  int tid = threadIdx.x;
  float rminv = 1.f / rowmean[i];
  const float4* wpr = (const float4*)(W_P + (size_t)i * N_);
  const float4* sr = (const float4*)(S + (size_t)i * N_);
  float local = 0.f;
  for (int j4 = tid; j4 < N_ / 4; j4 += 256) {
    float4 wp = wpr[j4], sv = sr[j4];
#pragma unroll
    for (int c = 0; c < 4; c++) {
      float s = ((const float*)&sv)[c] * rminv;
      float d = fmaxf(1.0f - s, 0.f);
      local += d * d + 0.5f * ((const float*)&wp)[c] * (s * s - d * d);
    }
  }
  __shared__ float red[256];
  red[tid] = local; __syncthreads();
  for (int st = 128; st > 0; st >>= 1) { if (tid < st) red[tid] += red[tid + st]; __syncthreads(); }
  if (tid == 0) partials[i] = red[0] - 0.5f;
}

// ---------- sparse W_C part: 0.5 * sum_v v*(C(i,col)+C(col,i)), C = s^2-d^2 ----------
// one thread per (i, mi, k); per-block partial sums (no atomics, all slots written)
__global__ __launch_bounds__(256) void sparse_wc_kernel(
    const int* __restrict__ idx, const int* __restrict__ nbr,
    const int* __restrict__ deg, const float* __restrict__ ovl,
    const float* __restrict__ S, const float* __restrict__ rowmean,
    float* __restrict__ sparse_partials) {
  int t = blockIdx.x * 256 + threadIdx.x;
  int i = t / (TOPK_HALF * TOPK);
  int r = t % (TOPK_HALF * TOPK);
  int mi = r / TOPK, k = r % TOPK;
  float contrib = 0.f;
  if (i < N_) {
    int m = idx[i * TOPK + mi];
    int dm = deg[m];
    if (k < dm) {
      int col = nbr[m * TOPK + k];
      if (col != i) {
        float v = ovl[m * TOPK + k] / (float)dm * 0.1f;  // W_C value at (i,col) & (col,i)
        float s1 = S[(size_t)i * N_ + col] / rowmean[i];
        float d1 = fmaxf(1.f - s1, 0.f);
        float s2 = S[(size_t)col * N_ + i] / rowmean[col];
        float d2 = fmaxf(1.f - s2, 0.f);
        contrib = 0.5f * v * ((s1 * s1 - d1 * d1) + (s2 * s2 - d2 * d2));
      }
    }
  }
  __shared__ float red[256];
  red[threadIdx.x] = contrib; __syncthreads();
  for (int st = 128; st > 0; st >>= 1) {
    if (threadIdx.x < st) red[threadIdx.x] += red[threadIdx.x + st];
    __syncthreads();
  }
  if (threadIdx.x == 0) sparse_partials[blockIdx.x] = red[0];
}

#define SPARSE_BLOCKS ((N_ * TOPK_HALF * TOPK) / 256)

__global__ __launch_bounds__(256) void finalize_kernel(const float* __restrict__ partials,
                                                       const float* __restrict__ sparse_partials,
                                                       float* __restrict__ out) {
  __shared__ float red[256];
  int tid = threadIdx.x;
  float s = 0.f;
  for (int i = tid; i < N_; i += 256) s += partials[i];
  for (int i = tid; i < SPARSE_BLOCKS; i += 256) s += sparse_partials[i];
  red[tid] = s; __syncthreads();
  for (int st = 128; st > 0; st >>= 1) { if (tid < st) red[tid] += red[tid + st]; __syncthreads(); }
  if (tid == 0) out[0] = red[0] / ((float)N_ * (float)(N_ - 1));
}

extern "C" void kernel_launch(void* const* d_in, const int* in_sizes, int n_in,
                              void* d_out, int out_size, void* d_ws, size_t ws_size,
                              hipStream_t stream) {
  const float* s_emb = (const float*)d_in[0];
  const float* t_emb = (const float*)d_in[1];
  float* out = (float*)d_out;

  const size_t NN = (size_t)N_ * N_;
  const size_t ND = (size_t)N_ * D_;
  short* t_bf = (short*)d_ws;                        // N*D bf16
  short* s_bf = t_bf + ND;                           // N*D bf16
  float* W_P = (float*)(s_bf + ND);                  // N*N
  float* S_raw = W_P + NN;                           // N*N
  float* tt = S_raw + NN;                            // N
  float* ss = tt + N_;                               // N
  float* rowmean = ss + N_;                          // N
  float* partials = rowmean + N_;                    // N
  float* sparse_partials = partials + N_;            // SPARSE_BLOCKS
  float* ovl = sparse_partials + SPARSE_BLOCKS;      // N*TOPK
  int* idx = (int*)(ovl + (size_t)N_ * TOPK);        // N*TOPK
  int* nbr = idx + (size_t)N_ * TOPK;                // N*TOPK
  int* deg = nbr + (size_t)N_ * TOPK;                // N

  tnorm_kernel<<<N_, 256, 0, stream>>>(t_emb, t_bf, tt);
  sconv_kernel<<<N_, 256, 0, stream>>>(s_emb, s_bf, ss);

  dim3 g(N_ / 128, N_ / 128, 2);
  gram_mfma_kernel<<<g, 256, 0, stream>>>(t_bf, s_bf, tt, ss, W_P, S_raw);

  topk_kernel<<<N_, 256, 0, stream>>>(W_P, idx);
  mutual_kernel<<<N_ / 256, 256, 0, stream>>>(idx, nbr, deg);
  overlap_kernel<<<(N_ * TOPK + 255) / 256, 256, 0, stream>>>(nbr, deg, ovl);

  rowmean_kernel<<<N_, 256, 0, stream>>>(S_raw, rowmean);
  loss_kernel<<<N_, 256, 0, stream>>>(W_P, S_raw, rowmean, partials);
  sparse_wc_kernel<<<SPARSE_BLOCKS, 256, 0, stream>>>(idx, nbr, deg, ovl, S_raw, rowmean,
                                                      sparse_partials);
  finalize_kernel<<<1, 256, 0, stream>>>(partials, sparse_partials, out);
}